// Round 14
// baseline (3887.675 us; speedup 1.0000x reference)
//
#include <hip/hip_runtime.h>
#include <hip/hip_bf16.h>
#include <cstdint>

// Neural ODE: 10 Heun steps of f(y) = tanh(y@W1 + b1)@W2 + b2
// BATCH=8192, D=512, H=2048, dt=0.1
// R20: FULL FUSION retry, enabled by R19's int8-W2. Weight set is now
// 3.1 MB < 4 MB per-XCD L2 => R17's thrash precondition (4 MB cyclic scan
// at exactly L2 capacity by desynced CUs -> 10.1 GB FETCH, L3-bound) is
// structurally gone. Single kernel, grid 256 x 1024; each block integrates
// its 32 rows through all 20 evals:
//  - y state in regs (ys[16] fp32); p carried in LDS ppL[reg*1024+tid]
//    (conflict-free stride-4B; avoids the VGPR squeeze that likely spilled
//    R17's reg-carried state at VGPR_Count=64).
//  - next eval input scattered straight into yA (R17's verified formula);
//    deletes per-eval: 16MB stateIn + 16MB stateOut + 8MB pack each way,
//    phase0 staging stall, epilogue drain tails (~4-7us/eval exposed IO).
//  - eval core byte-identical to R19: bf16 32x32x16 GEMM1, int8
//    mfma_i32_32x32x32 GEMM2 (h tanh-bounded, fixed scale 127; W2
//    per-column scale in epilogue). Math path identical => absmax should
//    be exactly 0.03515625.
// Discriminator: FETCH_SIZE total <100 MB (R17: 10.1 GB).
// Dead axes: schedule edits (R8/11/12/14/15), CW variants (R10/16), fp8
// (R18 accuracy), reg-batching >128 VGPR (R7/14).

#define BATCHN 8192
#define DDIM 512
#define HDIM 2048
#define CW 512          // chunk width over H
#define NCH (HDIM / CW) // 4
#define NEVAL 20        // 10 Heun steps x 2 f-evals

typedef short short8 __attribute__((ext_vector_type(8)));
typedef float floatx16 __attribute__((ext_vector_type(16)));
typedef int int4v __attribute__((ext_vector_type(4)));
typedef int intx16 __attribute__((ext_vector_type(16)));
typedef unsigned int uint2v __attribute__((ext_vector_type(2)));

__device__ __forceinline__ unsigned short f2bf(float f) {
  union { __hip_bfloat16 h; unsigned short u; } cv;
  cv.h = __float2bfloat16(f);
  return cv.u;
}

__device__ __forceinline__ float fast_tanh(float x) {
  float e = __expf(2.0f * x);
  return 1.0f - 2.0f / (e + 1.0f);
}

// 32x32 fragment conventions (bf16 verified R13+; i8 verified R19):
//  A-frag: lane holds A[m = lane&31][k-slice (lane>>5)], 8 bf16 / 16 i8
//  B-frag: lane holds B[n = lane&31][k-slice (lane>>5)]   (BT row-major)
//  C/D:    col = lane&31, row = (reg&3) + 8*(reg>>2) + 4*(lane>>5)
// Packed buffers: frag f at [(f*64 + lane)*elem] units.
//  w1p:   f = nb*32 + kb   (bf16; nb: 0..63, kb: 0..31)
//  w2p8:  f = nb*64 + kb   (int8; nb: 0..15, kb: 0..63, 16 B/lane, K=32)

__global__ __launch_bounds__(1024, 4) void fused_ode(
    const unsigned short* __restrict__ w1p,     // packed bf16 W1 (2 MB)
    const signed char* __restrict__ w2p8,       // packed int8 W2 (1 MB)
    const float* __restrict__ qsArr,            // per-col W2 scale (max/127)
    const float* __restrict__ b1,
    const float* __restrict__ b2,
    const float* __restrict__ y0,
    float* __restrict__ yOut) {
  __shared__ unsigned short yA[32 * 512];     // 32 KB, bf16 A32 frags
  __shared__ signed char hA8[2][32 * CW];     // 2 x 16 KB, int8 A32 frags
  __shared__ float ppL[16 * 1024];            // 64 KB, p carry (reg*1024+tid)

  const int tid  = threadIdx.x;
  const int lane = tid & 63;
  const int w    = tid >> 6;    // wave 0..15
  const int c31  = lane & 31;
  const int lhi  = lane >> 5;   // 0..1
  const int blk  = blockIdx.x;  // 0..255
  const int B0   = blk * 32;    // slab base row

  // Lane's output column and scatter constants (C/D layout).
  const int ncol = w * 32 + c31;          // 0..511
  const int ksf  = ncol >> 4;             // yA frag index
  const int lh   = (ncol >> 3) & 1;
  const int jj   = ncol & 7;
  const int mhi  = lhi * 4;

  // Loop-invariant scalars.
  float bb1v[NCH];
#pragma unroll
  for (int c = 0; c < NCH; ++c) bb1v[c] = b1[c * CW + ncol];
  const float bb2 = b2[ncol];
  const float sc = qsArr[ncol] * (1.0f / 127.0f);

  // Init: y0 slab -> ys regs (C/D layout) -> bf16 scatter into yA.
  float ys[16];
#pragma unroll
  for (int reg = 0; reg < 16; ++reg) {
    const int mrow = (reg & 3) + 8 * (reg >> 2) + mhi;
    ys[reg] = y0[(size_t)(B0 + mrow) * DDIM + ncol];
  }
#pragma unroll
  for (int reg = 0; reg < 16; ++reg) {
    const int mrow = (reg & 3) + 8 * (reg >> 2) + mhi;
    yA[(ksf * 64 + (mrow + 32 * lh)) * 8 + jj] = f2bf(ys[reg]);
  }
  __syncthreads();

#pragma unroll 1
  for (int e = 0; e < NEVAL; ++e) {
    intx16 accY = {};  // GEMM2 i32 acc: col = ncol, 16 rows (EXACT)

#pragma unroll
    for (int c = 0; c < NCH; ++c) {
      // ---- phase1 (bf16): acc1 = yA @ W1[:, (c*16+w)*32 .. +32] ----
      floatx16 acc1 = {};
      const unsigned short* w1b =
          w1p + ((size_t)((c * 16 + w) * 32) * 64 + lane) * 8;
#pragma unroll
      for (int ks = 0; ks < 32; ++ks) {
        short8 a = *(const short8*)&yA[(ks * 64 + lane) * 8];
        short8 b = *(const short8*)(w1b + (size_t)ks * 512);
        acc1 = __builtin_amdgcn_mfma_f32_32x32x16_bf16(a, b, acc1, 0, 0, 0);
      }

      // bias + tanh + int8 quant + scatter into hA8[c&1]
      {
        signed char* hbuf = hA8[c & 1];
        const float bb = bb1v[c];
        const int khalf = (c31 >> 4) << 5;   // 0 or 32
        const int jj8 = c31 & 15;
#pragma unroll
        for (int reg = 0; reg < 16; ++reg) {
          const int m = (reg & 3) + 8 * (reg >> 2) + mhi;   // C/D row
          const float hv = fast_tanh(acc1[reg] + bb);       // in (-1,1)
          hbuf[(w * 64 + khalf + m) * 16 + jj8] =
              (signed char)(int)rintf(hv * 127.0f);
        }
      }

      // ---- phase2 for chunk c-1: accY += h8_prev @ W2-slice (i8) ----
      if (c > 0) {
        const int cc = c - 1;
        const signed char* hp = hA8[cc & 1];
        const signed char* w2b =
            w2p8 + ((size_t)(w * 64 + cc * 16) * 64 + lane) * 16;
#pragma unroll
        for (int ks = 0; ks < 16; ++ks) {
          int4v a = *(const int4v*)&hp[(ks * 64 + lane) * 16];
          int4v b = *(const int4v*)(w2b + (size_t)ks * 1024);
          accY = __builtin_amdgcn_mfma_i32_32x32x32_i8(a, b, accY, 0, 0, 0);
        }
      }
      __syncthreads();
    }
    // tail phase2: chunk NCH-1 (buffer 1). Reads hA8 only — safe to run
    // while other waves scatter into yA below (yA reads all completed
    // before the last in-loop barrier).
    {
      const int cc = NCH - 1;
      const signed char* hp = hA8[cc & 1];
      const signed char* w2b =
          w2p8 + ((size_t)(w * 64 + cc * 16) * 64 + lane) * 16;
#pragma unroll
      for (int ks = 0; ks < 16; ++ks) {
        int4v a = *(const int4v*)&hp[(ks * 64 + lane) * 16];
        int4v b = *(const int4v*)(w2b + (size_t)ks * 1024);
        accY = __builtin_amdgcn_mfma_i32_32x32x32_i8(a, b, accY, 0, 0, 0);
      }
    }

    // Epilogue: descale + Heun combine; scatter next eval input into yA.
    // ppL slots and yA slots are lane-private writes (no races); the
    // e-loop-end barrier publishes yA to all waves for the next eval.
    if ((e & 1) == 0) {
      // eval1: v = k1. p = y + 0.05*k1 -> ppL; ymid = y + 0.1*k1 -> yA.
#pragma unroll
      for (int reg = 0; reg < 16; ++reg) {
        const int mrow = (reg & 3) + 8 * (reg >> 2) + mhi;
        const float v = (float)accY[reg] * sc + bb2;
        ppL[reg * 1024 + tid] = ys[reg] + 0.05f * v;
        const float nv = ys[reg] + 0.1f * v;   // ymid
        yA[(ksf * 64 + (mrow + 32 * lh)) * 8 + jj] = f2bf(nv);
      }
    } else {
      // eval2: v = k2. ynew = p + 0.05*k2 -> ys + yA.
#pragma unroll
      for (int reg = 0; reg < 16; ++reg) {
        const int mrow = (reg & 3) + 8 * (reg >> 2) + mhi;
        const float v = (float)accY[reg] * sc + bb2;
        const float yn = ppL[reg * 1024 + tid] + 0.05f * v;
        ys[reg] = yn;
        yA[(ksf * 64 + (mrow + 32 * lh)) * 8 + jj] = f2bf(yn);
      }
    }
    __syncthreads();  // yA(next input) visible; hA8 free for next eval
  }

  // Final store: ys holds y(t=1.0) fp32.
#pragma unroll
  for (int reg = 0; reg < 16; ++reg) {
    const int mrow = (reg & 3) + 8 * (reg >> 2) + mhi;
    yOut[(size_t)(B0 + mrow) * DDIM + ncol] = ys[reg];
  }
}

// Pack weight [K][N] fp32 -> 32x32 bf16 B-frag order (W1).
__global__ void pack_b(const float* __restrict__ src, unsigned short* __restrict__ dst,
                       int KB, int N) {
  const int t = blockIdx.x * 256 + threadIdx.x;
  const int lane = t & 63, f = t >> 6;
  const int nb = f / KB, kb = f % KB;
  const int k0 = kb * 16 + (lane >> 5) * 8, n = nb * 32 + (lane & 31);
  short8 v;
#pragma unroll
  for (int j = 0; j < 8; ++j)
    v[j] = (short)f2bf(src[(size_t)(k0 + j) * N + n]);
  *(short8*)&dst[(size_t)t * 8] = v;
}

// Zero the W2 column-max table.
__global__ void zero_cm(unsigned* __restrict__ cm) { cm[threadIdx.x] = 0u; }

// Per-column absmax of W2 [2048][512]: block b scans k in [b*16, b*16+16).
__global__ void colmax_w2(const float* __restrict__ w2, unsigned* __restrict__ cm) {
  const int n = threadIdx.x;          // 0..511
  const int k0 = blockIdx.x * 16;     // 128 blocks
  float m = 0.0f;
#pragma unroll
  for (int i = 0; i < 16; ++i) m = fmaxf(m, fabsf(w2[(size_t)(k0 + i) * DDIM + n]));
  atomicMax(&cm[n], __float_as_uint(m));
}

// Pack W2 [2048][512] fp32 -> int8 B-frags (f = nb*64 + kb, 16 B/lane)
// + emit qsArr[n]. lane entry = W2[kb*32 + (lane>>5)*16 + j][nb*32+(lane&31)].
__global__ void pack_w2i8(const float* __restrict__ w2, const unsigned* __restrict__ cm,
                          signed char* __restrict__ dst, float* __restrict__ qsArr) {
  const int t = blockIdx.x * 256 + threadIdx.x;  // 64K threads
  const int lane = t & 63, f = t >> 6;
  const int nb = f >> 6, kb = f & 63;
  const int n = nb * 32 + (lane & 31);
  const int k0 = kb * 32 + (lane >> 5) * 16;
  float qs = __uint_as_float(cm[n]) * (1.0f / 127.0f);
  if (qs <= 0.0f) qs = 1.0f;
  if (kb == 0 && (lane >> 5) == 0) qsArr[n] = qs;
  const float inv = 1.0f / qs;
  union { signed char b[16]; int4v v; } o;
#pragma unroll
  for (int j = 0; j < 16; ++j)
    o.b[j] = (signed char)(int)rintf(w2[(size_t)(k0 + j) * DDIM + n] * inv);
  *(int4v*)&dst[(size_t)t * 16] = o.v;
}

extern "C" void kernel_launch(void* const* d_in, const int* in_sizes, int n_in,
                              void* d_out, int out_size, void* d_ws, size_t ws_size,
                              hipStream_t stream) {
  const float* y0 = (const float*)d_in[0];
  const float* W1 = (const float*)d_in[1];  // [512][2048]
  const float* b1 = (const float*)d_in[2];  // [2048]
  const float* W2 = (const float*)d_in[3];  // [2048][512]
  const float* b2 = (const float*)d_in[4];  // [512]

  char* ws = (char*)d_ws;
  unsigned short* w1p   = (unsigned short*)(ws);                      // 2 MB
  signed char*    w2p8  = (signed char*)(ws + (size_t)(2u << 20));    // 1 MB
  float*          qsArr = (float*)(ws + (size_t)(3u << 20));          // 2 KB
  unsigned*       cmU   = (unsigned*)(ws + (size_t)(3u << 20) + 4096);

  // Pre-pass: W1 bf16 frags; W2 colmax -> int8 frags + qs table.
  zero_cm<<<1, 512, 0, stream>>>(cmU);
  colmax_w2<<<128, 512, 0, stream>>>(W2, cmU);
  pack_b<<<512, 256, 0, stream>>>(W1, w1p, 32, HDIM);
  pack_w2i8<<<256, 256, 0, stream>>>(W2, cmU, w2p8, qsArr);

  // Single fused integration kernel: 10 Heun steps, rows independent,
  // weight set (3.1 MB) L2-resident per XCD.
  fused_ode<<<dim3(256), dim3(1024), 0, stream>>>(
      w1p, w2p8, qsArr, b1, b2, y0, (float*)d_out);
}

// Round 15
// 931.275 us; speedup vs baseline: 4.1746x; 4.1746x over previous
//
#include <hip/hip_runtime.h>
#include <hip/hip_bf16.h>
#include <cstdint>

// Neural ODE: 10 Heun steps of f(y) = tanh(y@W1 + b1)@W2 + b2
// BATCH=8192, D=512, H=2048, dt=0.1
// R21 = R19 (int8 GEMM2, 989us) + int8 GEMM1:
//  - W1 int8 per-COLUMN scale (csW1[n]); y int8 per-ROW scale (rs[row] =
//    rowmax/127, computed in the producing dispatch's epilogue via
//    __shfl_xor max reduce + 1 LDS atomicMax per 32-lane group).
//  - GEMM1 dequant in epilogue: z = (f32)acc_i32 * rs_in[row] * csW1[col]
//    + b1. i32 accum exact. All scale indices static per reg/lane.
//  - Wins: W1 2->1 MB (weight stream 3.1->2.1 MB/CU/eval), GEMM1 MFMA
//    halves (K=32), yA LDS reads halve, pack traffic 8->4 MB.
//  - Error: rintf quant rms = absmax/(127*sqrt12) ~ 0.0075 sigma per
//    tensor; R19's analogous terms cost +0.004 absmax. Predict 0.05-0.08
//    vs threshold 0.126.
// R20 lesson (FETCH 7.9 GB): fusion desyncs blocks -> aggregate-fill LRU
// thrash of the per-XCD L2 even at 3.1 MB working set. Multi-launch
// phase-locks for free (launch overhead ~0). Fusion axis dead (R17, R20).
// Dead axes: schedule edits (R8/11/12/14/15), CW variants (R10/16), fp8
// (R18: mantissa-limited, scaling can't fix), reg-batching >128 VGPR.

#define BATCHN 8192
#define DDIM 512
#define HDIM 2048
#define CW 512          // chunk width over H
#define NCH (HDIM / CW) // 4

typedef short short8 __attribute__((ext_vector_type(8)));
typedef int int4v __attribute__((ext_vector_type(4)));
typedef int intx16 __attribute__((ext_vector_type(16)));

__device__ __forceinline__ float fast_tanh(float x) {
  float e = __expf(2.0f * x);
  return 1.0f - 2.0f / (e + 1.0f);
}

// 32x32 i8 fragment conventions (verified R19 GEMM2; A/B packed with the
// SAME assumed (lane,byte)->k bijection => k-permutation-invariant):
//  A-frag: lane holds A[m = lane&31][k = f*32 + (lane>>5)*16 + j], j=0..15
//  B-frag: lane holds B[n = lane&31][k = f*32 + (lane>>5)*16 + j]
//  C/D:    col = lane&31, row = (reg&3) + 8*(reg>>2) + 4*(lane>>5)
// Packed buffers: frag f at [(f*64 + lane)*16] bytes.
//  ypk8:  slab blk*16KB; f = ks (0..15 over D=512)
//  w1p8:  f = nb*16 + kb  (nb = H col-tile/32: 0..63, kb: 0..15)
//  w2p8:  f = nb*64 + kb  (nb = D col-tile/32: 0..15, kb: 0..63)

__global__ __launch_bounds__(1024, 4) void fused_feval(
    const signed char* __restrict__ in8,      // packed int8 eval input
    const float* __restrict__ rsIn,           // per-row input scale [8192]
    const signed char* __restrict__ w1p8,     // packed int8 W1 (1 MB)
    const float* __restrict__ csW1,           // per-col W1 scale [2048]
    const signed char* __restrict__ w2p8,     // packed int8 W2 (1 MB)
    const float* __restrict__ qs2,            // per-col W2 scale [512]
    const float* __restrict__ b1,
    const float* __restrict__ b2,
    const float* __restrict__ stateIn,   // EPI1: y fp32 ; EPI2: p fp32
    float* __restrict__ stateOut,        // EPI1: p      ; EPI2: ynew
    signed char* __restrict__ out8,      // packed int8 next-eval input
    float* __restrict__ rsOut,           // per-row output scale [8192]
    int epi) {                           // 1 or 2
  __shared__ signed char yA8[32 * 512];       // 16 KB, int8 A-frags
  __shared__ signed char hA8[2][32 * CW];     // 2 x 16 KB, int8 A-frags
  __shared__ unsigned rowmaxU[32];            // output row absmax (f32 bits)

  const int tid  = threadIdx.x;
  const int lane = tid & 63;
  const int w    = tid >> 6;    // wave 0..15
  const int c31  = lane & 31;
  const int lhi  = lane >> 5;   // 0..1
  const int blk  = blockIdx.x;  // 0..255
  const int B0   = blk * 32;    // slab base row

  // phase0: linear copy of this block's 16 KB packed y-slab into LDS.
  {
    const signed char* src = in8 + (size_t)blk * 16384;
    __builtin_amdgcn_global_load_lds(
        (const __attribute__((address_space(1))) void*)(uintptr_t)(src + (size_t)tid * 16),
        (__attribute__((address_space(3))) void*)(uint32_t)(uintptr_t)&yA8[tid * 16],
        16, 0, 0);
  }
  if (tid < 32) rowmaxU[tid] = 0u;

  // Loop-invariant scalars.
  const int ncol = w * 32 + c31;
  float bb1v[NCH], cw1v[NCH];
#pragma unroll
  for (int c = 0; c < NCH; ++c) {
    bb1v[c] = b1[c * CW + ncol];
    cw1v[c] = csW1[c * CW + ncol];
  }
  const float bb2 = b2[ncol];
  const float sc2 = qs2[ncol] * (1.0f / 127.0f);
  float rs_in[16];
#pragma unroll
  for (int reg = 0; reg < 16; ++reg) {
    const int mrow = (reg & 3) + 8 * (reg >> 2) + lhi * 4;
    rs_in[reg] = rsIn[B0 + mrow];
  }

  __syncthreads();

  intx16 accY = {};  // GEMM2 i32 acc: col = ncol, 16 rows (EXACT)

#pragma unroll
  for (int c = 0; c < NCH; ++c) {
    // ---- phase1 (i8): acc1 = y8 @ W1-slice, K=512 -> 16 MFMAs ----
    intx16 acc1 = {};
    const signed char* w1b =
        w1p8 + ((size_t)((c * 16 + w) * 16) * 64 + lane) * 16;
#pragma unroll
    for (int ks = 0; ks < 16; ++ks) {
      int4v a = *(const int4v*)&yA8[(ks * 64 + lane) * 16];
      int4v b = *(const int4v*)(w1b + (size_t)ks * 1024);
      acc1 = __builtin_amdgcn_mfma_i32_32x32x32_i8(a, b, acc1, 0, 0, 0);
    }

    // dequant + bias + tanh + h-quant (fixed 127) + scatter into hA8[c&1]
    {
      signed char* hbuf = hA8[c & 1];
      const float bb = bb1v[c];
      const float fa = cw1v[c];
      const int khalf = (c31 >> 4) << 5;   // 0 or 32
      const int jj8 = c31 & 15;
      const int mhi = lhi * 4;
#pragma unroll
      for (int reg = 0; reg < 16; ++reg) {
        const int m = (reg & 3) + 8 * (reg >> 2) + mhi;   // C/D row
        const float z = (float)acc1[reg] * (rs_in[reg] * fa) + bb;
        const float hv = fast_tanh(z);                    // in (-1,1)
        hbuf[(w * 64 + khalf + m) * 16 + jj8] =
            (signed char)(int)rintf(hv * 127.0f);
      }
    }

    // ---- phase2 for chunk c-1: accY += h8_prev @ W2-slice (i8) ----
    if (c > 0) {
      const int cc = c - 1;
      const signed char* hp = hA8[cc & 1];
      const signed char* w2b =
          w2p8 + ((size_t)(w * 64 + cc * 16) * 64 + lane) * 16;
#pragma unroll
      for (int ks = 0; ks < 16; ++ks) {
        int4v a = *(const int4v*)&hp[(ks * 64 + lane) * 16];
        int4v b = *(const int4v*)(w2b + (size_t)ks * 1024);
        accY = __builtin_amdgcn_mfma_i32_32x32x32_i8(a, b, accY, 0, 0, 0);
      }
    }
    __syncthreads();
  }
  // tail phase2: chunk NCH-1 (buffer 1); reads hA8[1] only.
  {
    const int cc = NCH - 1;
    const signed char* hp = hA8[cc & 1];
    const signed char* w2b =
        w2p8 + ((size_t)(w * 64 + cc * 16) * 64 + lane) * 16;
#pragma unroll
    for (int ks = 0; ks < 16; ++ks) {
      int4v a = *(const int4v*)&hp[(ks * 64 + lane) * 16];
      int4v b = *(const int4v*)(w2b + (size_t)ks * 1024);
      accY = __builtin_amdgcn_mfma_i32_32x32x32_i8(a, b, accY, 0, 0, 0);
    }
  }

  // Epilogue A: descale GEMM2, Heun combine (fp32 state path unchanged),
  // per-row absmax reduce of the next-eval input.
  float nv[16];
  {
    const int mhi = lhi * 4;
#pragma unroll
    for (int reg = 0; reg < 16; ++reg) {
      const int mrow = (reg & 3) + 8 * (reg >> 2) + mhi;
      const size_t idx = (size_t)(B0 + mrow) * DDIM + ncol;
      const float v = (float)accY[reg] * sc2 + bb2;
      if (epi == 1) {
        const float y = stateIn[idx];
        stateOut[idx] = y + 0.05f * v;   // p = y + (dt/2)*k1
        nv[reg] = y + 0.1f * v;          // ymid
      } else {
        const float yn = stateIn[idx] + 0.05f * v;  // ynew = p + (dt/2)*k2
        stateOut[idx] = yn;
        nv[reg] = yn;
      }
      float am = fabsf(nv[reg]);
      am = fmaxf(am, __shfl_xor(am, 1));
      am = fmaxf(am, __shfl_xor(am, 2));
      am = fmaxf(am, __shfl_xor(am, 4));
      am = fmaxf(am, __shfl_xor(am, 8));
      am = fmaxf(am, __shfl_xor(am, 16));
      if (c31 == 0) atomicMax(&rowmaxU[mrow], __float_as_uint(am));
    }
  }
  __syncthreads();  // rowmax final; all hA8 reads done

  // Epilogue B: quantize next input, scatter into staging, emit rsOut.
  {
    signed char* pbuf8 = &hA8[0][0];  // 16 KB staging, ypk8 A-frag layout
    const int khalf = (c31 >> 4) << 5;
    const int jj8 = c31 & 15;
    const int mhi = lhi * 4;
#pragma unroll
    for (int reg = 0; reg < 16; ++reg) {
      const int mrow = (reg & 3) + 8 * (reg >> 2) + mhi;
      const float mx = __uint_as_float(rowmaxU[mrow]);
      const float inv = (mx > 0.0f) ? (127.0f / mx) : 0.0f;
      pbuf8[(w * 64 + khalf + mrow) * 16 + jj8] =
          (signed char)(int)rintf(nv[reg] * inv);
    }
    if (tid < 32) {
      const float mx = __uint_as_float(rowmaxU[tid]);
      rsOut[B0 + tid] = ((mx > 0.0f) ? mx : 127.0f) * (1.0f / 127.0f);
    }
    __syncthreads();
    signed char* dst = out8 + (size_t)blk * 16384;
    *(int4v*)&dst[(size_t)tid * 16] = *(const int4v*)&pbuf8[(size_t)tid * 16];
  }
}

// ---- pre-pass kernels ----

__global__ void zero_u(unsigned* __restrict__ p, int n) {
  const int i = blockIdx.x * 1024 + threadIdx.x;
  if (i < n) p[i] = 0u;
}

// Per-column absmax of src [K][N] into cm[N] (f32 bits, atomicMax).
__global__ void colmax_g(const float* __restrict__ src, unsigned* __restrict__ cm,
                         int N) {
  const int n = blockIdx.y * blockDim.x + threadIdx.x;
  const int k0 = blockIdx.x * 16;
  float m = 0.0f;
#pragma unroll
  for (int i = 0; i < 16; ++i) m = fmaxf(m, fabsf(src[(size_t)(k0 + i) * N + n]));
  atomicMax(&cm[n], __float_as_uint(m));
}

// Pack weight [K][N] fp32 -> int8 B-frags (f = nb*KB + kb, 16 B/lane)
// + emit per-col scale scArr[n] = colmax/127.
__global__ void pack_bi8(const float* __restrict__ src, const unsigned* __restrict__ cm,
                         signed char* __restrict__ dst, float* __restrict__ scArr,
                         int KB, int N) {
  const int t = blockIdx.x * 256 + threadIdx.x;
  const int lane = t & 63, f = t >> 6;
  const int nb = f / KB, kb = f % KB;
  const int n = nb * 32 + (lane & 31);
  const int k0 = kb * 32 + (lane >> 5) * 16;
  const float mx = __uint_as_float(cm[n]);
  const float qs = (mx > 0.0f) ? mx * (1.0f / 127.0f) : 1.0f;
  if (kb == 0 && (lane >> 5) == 0) scArr[n] = qs;
  const float inv = 1.0f / qs;
  union { signed char b[16]; int4v v; } o;
#pragma unroll
  for (int j = 0; j < 16; ++j)
    o.b[j] = (signed char)(int)rintf(src[(size_t)(k0 + j) * N + n] * inv);
  *(int4v*)&dst[(size_t)t * 16] = o.v;
}

// Per-row absmax scale of y0: rs[row] = rowmax/127 (guarded positive).
__global__ void rowmax_y(const float* __restrict__ y0, float* __restrict__ rs) {
  const int tid = threadIdx.x;            // 512: 32 rows x 16 segs
  const int row = blockIdx.x * 32 + (tid >> 4);
  const int c0 = (tid & 15) * 32;
  float m = 0.0f;
#pragma unroll
  for (int j = 0; j < 32; ++j)
    m = fmaxf(m, fabsf(y0[(size_t)row * DDIM + c0 + j]));
  m = fmaxf(m, __shfl_xor(m, 1));
  m = fmaxf(m, __shfl_xor(m, 2));
  m = fmaxf(m, __shfl_xor(m, 4));
  m = fmaxf(m, __shfl_xor(m, 8));
  if ((tid & 15) == 0) rs[row] = ((m > 0.0f) ? m : 127.0f) * (1.0f / 127.0f);
}

// y0 fp32 -> yF fp32 copy + per-row-scaled int8 A-frags.
__global__ void pack_y8(const float* __restrict__ y0, const float* __restrict__ rs,
                        float* __restrict__ yF, signed char* __restrict__ dst) {
  const int t = blockIdx.x * 256 + threadIdx.x;  // 262144
  const int u = t & 1023, slab = t >> 10;
  const int f = u >> 6, lane = u & 63;
  const int row = slab * 32 + (lane & 31);
  const int c0 = f * 32 + (lane >> 5) * 16;
  const float inv = 1.0f / rs[row];   // rs > 0 guaranteed by rowmax_y
  union { signed char b[16]; int4v v; } o;
#pragma unroll
  for (int j = 0; j < 16; ++j) {
    const float x = y0[(size_t)row * DDIM + c0 + j];
    yF[(size_t)row * DDIM + c0 + j] = x;
    o.b[j] = (signed char)(int)rintf(x * inv);
  }
  *(int4v*)&dst[(size_t)t * 16] = o.v;
}

extern "C" void kernel_launch(void* const* d_in, const int* in_sizes, int n_in,
                              void* d_out, int out_size, void* d_ws, size_t ws_size,
                              hipStream_t stream) {
  const float* y0 = (const float*)d_in[0];
  const float* W1 = (const float*)d_in[1];  // [512][2048]
  const float* b1 = (const float*)d_in[2];  // [2048]
  const float* W2 = (const float*)d_in[3];  // [2048][512]
  const float* b2 = (const float*)d_in[4];  // [512]

  char* ws = (char*)d_ws;
  float*       yF    = (float*)(ws);                          // 16 MB
  float*       pF    = (float*)(ws + (size_t)(16u << 20));    // 16 MB
  signed char* ypk8  = (signed char*)(ws + (size_t)(32u << 20)); // 4 MB
  signed char* ympk8 = (signed char*)(ws + (size_t)(36u << 20)); // 4 MB
  signed char* w1p8  = (signed char*)(ws + (size_t)(40u << 20)); // 1 MB
  signed char* w2p8  = (signed char*)(ws + (size_t)(41u << 20)); // 1 MB
  float*       csW1  = (float*)(ws + (size_t)(42u << 20));    // 8 KB
  float*       qs2   = (float*)(ws + (size_t)(42u << 20) + 16384);   // 2 KB
  unsigned*    cmU   = (unsigned*)(ws + (size_t)(42u << 20) + 32768); // 10 KB
  float*       rsA   = (float*)(ws + (size_t)(43u << 20));    // 32 KB
  float*       rsB   = (float*)(ws + (size_t)(43u << 20) + 65536);   // 32 KB

  // Pre-pass: col scales + int8 packs for W1/W2; row scales + pack for y0.
  zero_u<<<3, 1024, 0, stream>>>(cmU, 2560);
  colmax_g<<<dim3(32, 4), 512, 0, stream>>>(W1, cmU, HDIM);
  colmax_g<<<dim3(128, 1), 512, 0, stream>>>(W2, cmU + 2048, DDIM);
  pack_bi8<<<256, 256, 0, stream>>>(W1, cmU, w1p8, csW1, 16, HDIM);
  pack_bi8<<<256, 256, 0, stream>>>(W2, cmU + 2048, w2p8, qs2, 64, DDIM);
  rowmax_y<<<256, 512, 0, stream>>>(y0, rsA);
  pack_y8<<<1024, 256, 0, stream>>>(y0, rsA, yF, ypk8);

  const dim3 grid(256), blkd(1024);
  for (int s = 0; s < 10; ++s) {
    // eval1: k1 = f(y); p = y + 0.05*k1; ymid -> int8 pack + rsB
    fused_feval<<<grid, blkd, 0, stream>>>(ypk8, rsA, w1p8, csW1, w2p8, qs2,
                                           b1, b2, yF, pF, ympk8, rsB, 1);
    // eval2: k2 = f(ymid); ynew = p + 0.05*k2 -> fp32 + int8 pack + rsA
    float* yOut = (s == 9) ? (float*)d_out : yF;
    fused_feval<<<grid, blkd, 0, stream>>>(ympk8, rsB, w1p8, csW1, w2p8, qs2,
                                           b1, b2, pF, yOut, ypk8, rsA, 2);
  }
}